// Round 7
// baseline (254.414 us; speedup 1.0000x reference)
//
#include <hip/hip_runtime.h>

// Problem constants (B,C,H,W = 32,64,128,128)
static constexpr int Cc  = 64;
static constexpr int HWc = 16384;   // 128*128
static constexpr int Bc  = 32;
static constexpr int PXB = 1024;    // pixels per block
static constexpr int PH  = 64;      // pixels per phase
static constexpr int NPH = PXB / PH;  // 16 phases

// ---------------------------------------------------------------------------
// Identity (verified): sigmoid(d)+sigmoid(-d)=1 makes A[b] = -0.5*theta, so
// out[b,n,:] = W_lin @ relu(-0.5*theta @ x[b,:,n]) + b_lin.
// Round 9 = r6 (verified: WRITE exactly 128 MiB, coalesced 1KB stores) + ONE
// change: NON-TEMPORAL full-line stores.
//   Theory: working set x(134MB)+out(128MB) = 262MB > 256MB L3. out's
//   write-allocate continuously evicts x -> FETCH_SIZE pinned at 65MB every
//   round: 65MB of HBM reads interleaved into the write stream (mixed
//   read/write + 64KB-strided reads = worst HBM efficiency regime; pure-write
//   fillBuffer hits 6.6 TB/s at 9% occupancy, we get 2.2). NT full-line
//   stores skip L3 allocation -> x fully L3-resident -> HBM becomes a pure
//   write stream. r3's NT failed because its stores were 16B scatters
//   (partial-line NT -> WRITE grew 132->158MB, proving nt does bypass);
//   r6's stores are 16 complete lines per instr -> no partial-line penalty.
//   Prediction: FETCH 65.6MB -> <15MB (smoking gun), WRITE unchanged
//   131072KB, dur 92.5 -> 55-70us.
// Pipeline (unchanged from r5/r6): per phase (a) issue 16 gload_lds width-4
//   for next 64-px tile -> (b) compute current -> (w) s_waitcnt vmcnt(4)
//   (4 newest = own stores, never waited; in-order retirement proves gloads
//   landed) -> (s) raw s_barrier. No vmcnt-0 drain in the loop.
// mfma_f32_16x16x32_f16 layouts (HW-verified):
//   A[m=lane&15][k=quad*8+j]  B[col=lane&15][k=quad*8+j]  D[row=quad*4+r][col=lane&15]
// GEMM1 (swapped): D1 = M1 @ x   -> lane holds P[n][i=4quad+r(+16it)]
// GEMM2 (swapped): D2 = W  @ P^T -> lane holds out[n][c=4quad+r(+16ct)]
// LDS: xbuf rows 65 dw (pad survives gload_lds linear-dest rule: one instr
//   per row; frag b32 reads 2-way = free); M1l/Wl stride 72 f16; scr union
//   {p2[16][72] f16, ot[16][68] f32} per wave, temporally disjoint, same-wave
//   DS ordering -> no barrier. LDS 69120 B -> 2 blocks/CU; grid 512 = 2/CU.
// ---------------------------------------------------------------------------

typedef _Float16 v8h __attribute__((ext_vector_type(8)));
typedef float    v4f __attribute__((ext_vector_type(4)));

union FragU { uint32_t u[4]; v8h h; };
union Scr {
  _Float16 p2[16][72];   // 2304 B: P tile [n][i], GEMM1 out / GEMM2 A-in
  float    ot[16][68];   // 4352 B: out tile [n][c], GEMM2 out / store-stage
};

__device__ inline uint32_t packf2(float lo, float hi) {
  union { _Float16 h[2]; uint32_t u; } r;
  r.h[0] = (_Float16)lo; r.h[1] = (_Float16)hi;
  return r.u;
}

__device__ inline v4f mfma16(v8h a, v8h b, v4f c) {
  return __builtin_amdgcn_mfma_f32_16x16x32_f16(a, b, c, 0, 0, 0);
}

// width-4 global->LDS: lane i reads 4B at its own gptr, HW writes ldsbase+i*4.
__device__ inline void gload_lds4(const float* g, float* l) {
  __builtin_amdgcn_global_load_lds(
      (const __attribute__((address_space(1))) void*)g,
      (__attribute__((address_space(3))) void*)l, 4, 0, 0);
}

// Prep: f16 weights. M1h = -0.5*theta (row-major [i][c]); Wh = W_lin ([c][i]).
__global__ void prep_weights(const float* __restrict__ theta,
                             const float* __restrict__ Wlin,
                             _Float16* __restrict__ M1h,
                             _Float16* __restrict__ Wh) {
  int t = blockIdx.x * 256 + threadIdx.x;
  if (t < Cc * Cc) {
    M1h[t] = (_Float16)(-0.5f * theta[t]);
    Wh[t]  = (_Float16)(Wlin[t]);
  }
}

__global__ __launch_bounds__(256) void fused_mfma(
    const float* __restrict__ x,      // [B, C, HW]
    const _Float16* __restrict__ M1h, // [64][64]
    const _Float16* __restrict__ Wh,  // [64][64]
    const float* __restrict__ blin,   // [64]
    float* __restrict__ out)          // [B, HW, C]
{
  __shared__ __align__(16) float    xbuf[2][64][65];  // 33280 B, dbuf x tile (f32)
  __shared__ __align__(16) _Float16 M1l[64][72];      //  9216 B
  __shared__ __align__(16) _Float16 Wl [64][72];      //  9216 B
  __shared__ __align__(16) Scr      scr[4];           // 17408 B (per-wave)

  const int tid  = threadIdx.x;
  const int wv   = tid >> 6;
  const int l    = tid & 63;
  const int lq   = tid & 15;
  const int quad = l >> 4;
  const int pxw  = wv * 16 + lq;    // this wave's pixel within the phase

  const int b   = blockIdx.x >> 4;          // 16 blocks per batch
  const int px0 = (blockIdx.x & 15) * PXB;
  const float* xb = x + (size_t)b * Cc * HWc;

  // ---- stage weights into LDS (two uint4 per 16-element segment)
  {
    const int r = tid >> 2, seg = (tid & 3) * 16;
    const uint4 m0 = *(const uint4*)(M1h + r * 64 + seg);
    const uint4 m1 = *(const uint4*)(M1h + r * 64 + seg + 8);
    const uint4 w0 = *(const uint4*)(Wh  + r * 64 + seg);
    const uint4 w1 = *(const uint4*)(Wh  + r * 64 + seg + 8);
    *(uint4*)&M1l[r][seg]     = m0;
    *(uint4*)&M1l[r][seg + 8] = m1;
    *(uint4*)&Wl[r][seg]      = w0;
    *(uint4*)&Wl[r][seg + 8]  = w1;
  }
  v4f bias4[4];
#pragma unroll
  for (int ct = 0; ct < 4; ++ct)
    bias4[ct] = *(const v4f*)(blin + ct * 16 + quad * 4);

  // ---- prologue: stage phase 0 (wave wv stages rows [16wv,16wv+16))
#pragma unroll
  for (int i = 0; i < 16; ++i) {
    const int c = wv * 16 + i;
    gload_lds4(xb + (size_t)c * HWc + px0 + l, &xbuf[0][c][0]);
  }

  __syncthreads();   // drains prologue gloads + weight staging; the only full sync

  for (int t = 0; t < NPH; ++t) {
    // ---- (a) issue next phase's staging FIRST; stays in flight through (b)
    if (t < NPH - 1) {
      const int pb = px0 + (t + 1) * PH;
      float* dst = &xbuf[(t + 1) & 1][0][0];
#pragma unroll
      for (int i = 0; i < 16; ++i) {
        const int c = wv * 16 + i;
        gload_lds4(xb + (size_t)c * HWc + pb + l, dst + c * 65);
      }
      __builtin_amdgcn_sched_barrier(0);   // pin issue-early
    }

    // ---- (b) compute phase t from xbuf[t&1] (valid since barrier of t-1)
    const int kb = t & 1;
    FragU xf[2];
#pragma unroll
    for (int kt = 0; kt < 2; ++kt)
#pragma unroll
      for (int r = 0; r < 4; ++r) {
        const int c0 = kt * 32 + quad * 8 + 2 * r;
        xf[kt].u[r] = packf2(xbuf[kb][c0][pxw], xbuf[kb][c0 + 1][pxw]);  // RTE f16
      }

    // GEMM1: D1[i][n] = M1 @ x ; relu+pack -> p2[n][i] (b64 writes)
#pragma unroll
    for (int it = 0; it < 4; ++it) {
      v4f a = {0.f, 0.f, 0.f, 0.f};
#pragma unroll
      for (int kt = 0; kt < 2; ++kt)
        a = mfma16(*(const v8h*)&M1l[it * 16 + lq][kt * 32 + quad * 8],
                   xf[kt].h, a);
      uint2 w;
      w.x = packf2(fmaxf(a[0], 0.f), fmaxf(a[1], 0.f));
      w.y = packf2(fmaxf(a[2], 0.f), fmaxf(a[3], 0.f));
      *(uint2*)&scr[wv].p2[lq][it * 16 + quad * 4] = w;
    }

    // P A-frags: read BEFORE any ot write (same-wave DS ordering; p2/ot alias)
    FragU pr[2];
#pragma unroll
    for (int kt = 0; kt < 2; ++kt)
      pr[kt].h = *(const v8h*)&scr[wv].p2[lq][kt * 32 + quad * 8];

    // GEMM2: D2[c][n] = W @ P^T -> lane holds out[pxw][ct*16+quad*4 .. +3]
    // Stage into per-wave ot (b128 LDS writes), then coalesced NT stores.
#pragma unroll
    for (int ct = 0; ct < 4; ++ct) {
      v4f a = bias4[ct];
#pragma unroll
      for (int kt = 0; kt < 2; ++kt)
        a = mfma16(*(const v8h*)&Wl[ct * 16 + lq][kt * 32 + quad * 8],
                   pr[kt].h, a);
      *(v4f*)&scr[wv].ot[lq][ct * 16 + quad * 4] = a;
    }

    // ---- coalesced NON-TEMPORAL store epilogue: wave's 16 px x 256B = 4KB
    // contiguous. Lane l, instr i reads ot[(l>>4)+4i][(l&15)*4] == out-linear
    // dword i*256+4l -> 4 x 1KB stores, 16 full 64B lines each, nt flag =
    // no L3 allocation -> x stays L3-resident, HBM sees a pure write stream.
    {
      float* obase = out + ((size_t)b * HWc + px0 + t * PH + wv * 16) * Cc;
#pragma unroll
      for (int i = 0; i < 4; ++i) {
        const v4f v = *(const v4f*)&scr[wv].ot[(l >> 4) + 4 * i][(l & 15) * 4];
        __builtin_nontemporal_store(v, (v4f*)(obase + i * 256 + l * 4));
      }
    }

    // ---- (w)+(s): counted wait (own gloads done; 4 newest = own NT stores,
    //      never waited) then RAW barrier -> next tile globally valid.
    if (t < NPH - 1) {
      asm volatile("s_waitcnt vmcnt(4)" ::: "memory");
      __builtin_amdgcn_sched_barrier(0);
      __builtin_amdgcn_s_barrier();
      __builtin_amdgcn_sched_barrier(0);
    }
  }
}

extern "C" void kernel_launch(void* const* d_in, const int* in_sizes, int n_in,
                              void* d_out, int out_size, void* d_ws, size_t ws_size,
                              hipStream_t stream) {
  const float* x     = (const float*)d_in[0];
  const float* theta = (const float*)d_in[1];
  const float* W_lin = (const float*)d_in[2];
  const float* b_lin = (const float*)d_in[3];
  float* out = (float*)d_out;

  _Float16* M1h = (_Float16*)d_ws;
  _Float16* Wh  = M1h + Cc * Cc;

  prep_weights<<<(Cc * Cc + 255) / 256, 256, 0, stream>>>(theta, W_lin, M1h, Wh);

  const int nblocks = Bc * HWc / PXB;   // 512 blocks = exactly 2/CU, zero tail
  fused_mfma<<<nblocks, 256, 0, stream>>>(x, M1h, Wh, b_lin, out);
}

// Round 8
// 251.791 us; speedup vs baseline: 1.0104x; 1.0104x over previous
//
#include <hip/hip_runtime.h>

// Problem constants (B,C,H,W = 32,64,128,128)
static constexpr int Cc  = 64;
static constexpr int HWc = 16384;   // 128*128
static constexpr int Bc  = 32;
static constexpr int PXB = 1024;    // pixels per block
static constexpr int PH  = 256;     // pixels per phase (=> 1KB/instr reads)
static constexpr int NPH = PXB / PH;  // 4 phases

// ---------------------------------------------------------------------------
// Identity (verified): sigmoid(d)+sigmoid(-d)=1 makes A[b] = -0.5*theta, so
// out[b,n,:] = W_lin @ relu(-0.5*theta @ x[b,:,n]) + b_lin.
// Round 10: REQUEST-SIZE theory. r5-r7 proved concurrency is ample (~32KB/CU
// in flight) yet BW pinned at 2.2 TB/s -> the system serves our requests
// slowly. Correlation across rounds: per-instruction request size 1KB (r0,
// 80us) > 512B (r1, 85) > 256B (r5-r7 gload_lds width-4, 92-96). A per-CU
// outstanding-REQUEST limit ~32 gives 32*256B/900ns = 2.3 TB/s chip = the
// invariant. Fix: 16B/lane float4 loads (1KB/request) inside the counted
// pipeline:
//   per phase: (1) issue 16 float4 loads for phase t+1 -> sched_barrier pin
//   (2) compute phase t (frag ds_reads, GEMM1, p2, GEMM2, 16 full-line
//   stores) (3) pack -> 8 ds_write_b128 into xbuf[t+1&1]; the compiler's own
//   PRECISE vmcnt covers the loads -- the stores are YOUNGER in-order vmem
//   ops, so no load-wait can block on them (4) asm lgkmcnt(0) + raw
//   s_barrier: NO vmcnt-0 drain ever (that was r1/r2's serializer).
// mfma_f32_16x16x32_f16 layouts (HW-verified):
//   A[m=lane&15][k=quad*8+j]  B[col=lane&15][k=quad*8+j]  D[row=quad*4+r][col=lane&15]
// GEMM1 (swapped): D1 = M1 @ x   -> lane holds P[n][i=4quad+r(+16it)]
// GEMM2 (swapped): D2 = W  @ P^T -> lane holds out[n][c=4quad+r(+16ct)];
//   each store instr covers 16 complete 64B line-segments (verified r5/r6).
// LDS: xbuf[2][32 ch-pairs][260] u32 (1040B rows, 16B-aligned; frag b32
//   reads 2-way = free [r0-verified]); p2 stride 72 f16 per wave (same-wave
//   DS ordering, no barrier). 66560+9216 = 75776 B -> 2 blocks/CU.
// Weights in registers (64 VGPR) -- budget 256 at 2 waves/SIMD, no remat.
// Grid 512 = exactly 2/CU, zero tail. launch_bounds(256,2).
// ---------------------------------------------------------------------------

typedef _Float16 v8h __attribute__((ext_vector_type(8)));
typedef float    v4f __attribute__((ext_vector_type(4)));

union FragU { uint32_t u[4]; v8h h; };

__device__ inline uint32_t packf2(float lo, float hi) {
  union { _Float16 h[2]; uint32_t u; } r;
  r.h[0] = (_Float16)lo; r.h[1] = (_Float16)hi;
  return r.u;
}

__device__ inline v4f mfma16(v8h a, v8h b, v4f c) {
  return __builtin_amdgcn_mfma_f32_16x16x32_f16(a, b, c, 0, 0, 0);
}

// Prep: f16 weights. M1h = -0.5*theta (row-major [i][c]); Wh = W_lin ([c][i]).
__global__ void prep_weights(const float* __restrict__ theta,
                             const float* __restrict__ Wlin,
                             _Float16* __restrict__ M1h,
                             _Float16* __restrict__ Wh) {
  int t = blockIdx.x * 256 + threadIdx.x;
  if (t < Cc * Cc) {
    M1h[t] = (_Float16)(-0.5f * theta[t]);
    Wh[t]  = (_Float16)(Wlin[t]);
  }
}

__global__ __launch_bounds__(256, 2) void fused_mfma(
    const float* __restrict__ x,      // [B, C, HW]
    const _Float16* __restrict__ M1h, // [64][64]
    const _Float16* __restrict__ Wh,  // [64][64]
    const float* __restrict__ blin,   // [64]
    float* __restrict__ out)          // [B, HW, C]
{
  __shared__ __align__(16) uint32_t xbuf[2][32][260];  // 66560 B, f16x2 ch-pairs
  __shared__ __align__(16) _Float16 p2[4][16][72];     //  9216 B (per-wave)

  const int tid  = threadIdx.x;
  const int wv   = tid >> 6;
  const int l    = tid & 63;
  const int lq   = tid & 15;
  const int quad = l >> 4;

  const int b   = blockIdx.x >> 4;          // 16 blocks per batch
  const int px0 = (blockIdx.x & 15) * PXB;
  const float* xb = x + (size_t)b * Cc * HWc;

  // ---- weights + bias in registers (r0-verified frag mapping)
  const v8h* M1v = (const v8h*)M1h;
  const v8h* Whv = (const v8h*)Wh;
  v8h w1[4][2], w2[4][2];
#pragma unroll
  for (int it = 0; it < 4; ++it)
#pragma unroll
    for (int kt = 0; kt < 2; ++kt) {
      w1[it][kt] = M1v[(it * 16 + lq) * 8 + kt * 4 + quad];  // M1[i][c] A-frag
      w2[it][kt] = Whv[(it * 16 + lq) * 8 + kt * 4 + quad];  // W[c][i]  A-frag
    }
  v4f bias4[4];
#pragma unroll
  for (int ct = 0; ct < 4; ++ct)
    bias4[ct] = *(const v4f*)(blin + ct * 16 + quad * 4);

  // ---- prologue: stage phase 0. Wave wv stages channel-pairs [8wv, 8wv+8).
  // Each load: 64 lanes x 16B = 1KB contiguous (lane l -> px 4l..4l+3).
  {
    float4 pe[8], po[8];
#pragma unroll
    for (int i = 0; i < 8; ++i) {
      const int p = wv * 8 + i;
      pe[i] = *(const float4*)(xb + (size_t)(2 * p)     * HWc + px0 + 4 * l);
      po[i] = *(const float4*)(xb + (size_t)(2 * p + 1) * HWc + px0 + 4 * l);
    }
#pragma unroll
    for (int i = 0; i < 8; ++i) {
      uint4 w;
      w.x = packf2(pe[i].x, po[i].x); w.y = packf2(pe[i].y, po[i].y);
      w.z = packf2(pe[i].z, po[i].z); w.w = packf2(pe[i].w, po[i].w);
      *(uint4*)&xbuf[0][wv * 8 + i][4 * l] = w;
    }
  }
  __syncthreads();   // prologue only; full drain is fine here

  for (int t = 0; t < NPH; ++t) {
    const int kb = t & 1;

    // ---- (1) issue next phase's 16 x 1KB loads; pin early
    float4 pe[8], po[8];
    if (t < NPH - 1) {
      const int pb = px0 + (t + 1) * PH;
#pragma unroll
      for (int i = 0; i < 8; ++i) {
        const int p = wv * 8 + i;
        pe[i] = *(const float4*)(xb + (size_t)(2 * p)     * HWc + pb + 4 * l);
        po[i] = *(const float4*)(xb + (size_t)(2 * p + 1) * HWc + pb + 4 * l);
      }
      __builtin_amdgcn_sched_barrier(0);
    }

    // ---- (2) compute phase t: wave wv owns px [64wv, 64wv+64) of the phase
    const int nb = wv * 64;
#pragma unroll
    for (int nt = 0; nt < 4; ++nt) {
      // x B-frags: u32 reg r = channel-pair kt*16+quad*4+r at pixel nb+16nt+lq
      FragU xf[2];
#pragma unroll
      for (int kt = 0; kt < 2; ++kt)
#pragma unroll
        for (int r = 0; r < 4; ++r)
          xf[kt].u[r] = xbuf[kb][kt * 16 + quad * 4 + r][nb + nt * 16 + lq];

      // GEMM1: D1[i][n] = M1 @ x ; relu+pack -> p2[n][i] (b64 writes)
#pragma unroll
      for (int it = 0; it < 4; ++it) {
        v4f a = {0.f, 0.f, 0.f, 0.f};
        a = mfma16(w1[it][0], xf[0].h, a);
        a = mfma16(w1[it][1], xf[1].h, a);
        uint2 w;
        w.x = packf2(fmaxf(a[0], 0.f), fmaxf(a[1], 0.f));
        w.y = packf2(fmaxf(a[2], 0.f), fmaxf(a[3], 0.f));
        *(uint2*)&p2[wv][lq][it * 16 + quad * 4] = w;
      }

      // P A-frags (in-wave DS ordering; p2 per-wave -> no barrier)
      FragU pr[2];
      pr[0].h = *(const v8h*)&p2[wv][lq][quad * 8];
      pr[1].h = *(const v8h*)&p2[wv][lq][32 + quad * 8];

      // GEMM2: D2[c][n] = W @ P^T -> out[n][c]; each instr = 16 full 64B
      // line-segments (4 quads cover each 64B c-span per pixel).
      float* orow = out + ((size_t)b * HWc + px0 + t * PH + nb + nt * 16 + lq) * Cc
                    + quad * 4;
#pragma unroll
      for (int ct = 0; ct < 4; ++ct) {
        v4f a = bias4[ct];
        a = mfma16(w2[ct][0], pr[0].h, a);
        a = mfma16(w2[ct][1], pr[1].h, a);
        *(v4f*)(orow + ct * 16) = a;
      }
    }

    // ---- (3) pack + ds_write next tile. Compiler emits PRECISE counted
    // vmcnt for pe/po (stores are younger in-order ops -> never waited).
    // ---- (4) lgkmcnt(0) + raw s_barrier: cross-wave LDS visibility with
    // NO vmcnt-0 store drain.
    if (t < NPH - 1) {
#pragma unroll
      for (int i = 0; i < 8; ++i) {
        uint4 w;
        w.x = packf2(pe[i].x, po[i].x); w.y = packf2(pe[i].y, po[i].y);
        w.z = packf2(pe[i].z, po[i].z); w.w = packf2(pe[i].w, po[i].w);
        *(uint4*)&xbuf[kb ^ 1][wv * 8 + i][4 * l] = w;
      }
      asm volatile("s_waitcnt lgkmcnt(0)" ::: "memory");
      __builtin_amdgcn_s_barrier();
      __builtin_amdgcn_sched_barrier(0);
    }
  }
}

extern "C" void kernel_launch(void* const* d_in, const int* in_sizes, int n_in,
                              void* d_out, int out_size, void* d_ws, size_t ws_size,
                              hipStream_t stream) {
  const float* x     = (const float*)d_in[0];
  const float* theta = (const float*)d_in[1];
  const float* W_lin = (const float*)d_in[2];
  const float* b_lin = (const float*)d_in[3];
  float* out = (float*)d_out;

  _Float16* M1h = (_Float16*)d_ws;
  _Float16* Wh  = M1h + Cc * Cc;

  prep_weights<<<(Cc * Cc + 255) / 256, 256, 0, stream>>>(theta, W_lin, M1h, Wh);

  const int nblocks = Bc * HWc / PXB;   // 512 blocks = exactly 2/CU, zero tail
  fused_mfma<<<nblocks, 256, 0, stream>>>(x, M1h, Wh, b_lin, out);
}